// Round 4
// baseline (246.973 us; speedup 1.0000x reference)
//
#include <hip/hip_runtime.h>

// ---------------------------------------------------------------------------
// MHA forward, fp32 I/O.  S=4096, D=1024, NH=16, HD=64.
// R16: GEMM residency fix.  R15's core ran ~275 TF because 64KB LDS ->
// 2 blocks/CU and grid 768 -> 1.5 rounds: no cross-block overlap to hide
// the vmcnt(0) drain at each K-step barrier (m114).  BK 64->32 halves
// LDS: proj3 35KB -> 3 blocks/CU, one exact round; gemm_out retiled
// 64x64 (16KB) grid 1024 -> 4 blocks/CU.  Swizzle re-derived for 64B
// rows: stage chunk ^= (row>>1)&3, read slot = quad ^ ((l15>>1)&3)
// -> 2-way max (free).  attn: per-iter softmax-denominator reduction
// (32 f32 adds + shfl, on the critical VALU pipe) moved to the idle
// MFMA pipe via l_acc = mfma(ones, pf, l_acc).
// ---------------------------------------------------------------------------

typedef unsigned short ushort_t;
typedef unsigned short ushort4v __attribute__((ext_vector_type(4)));
typedef unsigned short ushort8 __attribute__((ext_vector_type(8)));
typedef __bf16 bf16x8 __attribute__((ext_vector_type(8)));
typedef float f32x4 __attribute__((ext_vector_type(4)));
typedef float f32x16 __attribute__((ext_vector_type(16)));
typedef unsigned int uint4v __attribute__((ext_vector_type(4)));

#define SEQ 4096
#define DIM 1024
#define NH 16
#define HD 64
// 0.125 * log2(e): folded into Q projection so softmax uses exp2 directly
#define QSCALE 0.18033688011112042f

__device__ inline ushort_t fcvt(float f) {           // native f32->bf16 RTNE
    return __builtin_bit_cast(ushort_t, (__bf16)f);
}
__device__ inline bf16x8 frag_of(ushort8 t) {
    return __builtin_bit_cast(bf16x8, t);
}
__device__ inline bf16x8 lds_frag(const ushort_t* p) {
    return frag_of(*(const ushort8*)p);
}
__device__ inline unsigned pk2(float a, float b) {   // packed bf16 pair
    return (unsigned)fcvt(a) | ((unsigned)fcvt(b) << 16);
}
// swap lanes 32-63 of a with lanes 0-31 of b (gfx950 cross-lane op)
__device__ inline void plswap(unsigned& a, unsigned& b) {
    asm("v_permlane32_swap_b32 %0, %1" : "+v"(a), "+v"(b));
}
// swizzled elem offset within a linear [64][64] bf16 LDS tile (attn)
__device__ inline int swz(int row, int col) {
    return row * 64 + (col ^ ((row & 7) << 3));
}
// async global->LDS, 16B per lane; LDS dest = wave-uniform base + lane*16
__device__ __attribute__((always_inline)) inline void gload16(
    const ushort_t* g, ushort_t* l)
{
    __builtin_amdgcn_global_load_lds(
        (const __attribute__((address_space(1))) void*)g,
        (__attribute__((address_space(3))) void*)l, 16, 0, 0);
}

// ---------------------------------------------------------------------------
// Prep: f32 -> bf16 converts
// ---------------------------------------------------------------------------
__global__ __launch_bounds__(256) void cvt2(
    const float* __restrict__ s0, ushort_t* __restrict__ d0,
    const float* __restrict__ s1, ushort_t* __restrict__ d1, int n8)
{
    const float* s = blockIdx.y ? s1 : s0;
    ushort_t*    d = blockIdx.y ? d1 : d0;
    int i = blockIdx.x * 256 + threadIdx.x;
    if (i >= n8) return;
    const f32x4* sp = (const f32x4*)s + (size_t)i * 2;
    f32x4 a = sp[0], b = sp[1];
    ushort8 o;
    for (int k = 0; k < 4; ++k) { o[k] = fcvt(a[k]); o[k + 4] = fcvt(b[k]); }
    *((ushort8*)d + i) = o;
}

__global__ __launch_bounds__(256) void cvt4(
    const float* __restrict__ s0, ushort_t* __restrict__ d0,
    const float* __restrict__ s1, ushort_t* __restrict__ d1,
    const float* __restrict__ s2, ushort_t* __restrict__ d2,
    const float* __restrict__ s3, ushort_t* __restrict__ d3, int n8)
{
    const float* ss[4] = {s0, s1, s2, s3};
    ushort_t*    dd[4] = {d0, d1, d2, d3};
    const float* s = ss[blockIdx.y];
    ushort_t*    d = dd[blockIdx.y];
    int i = blockIdx.x * 256 + threadIdx.x;
    if (i >= n8) return;
    const f32x4* sp = (const f32x4*)s + (size_t)i * 2;
    f32x4 a = sp[0], b = sp[1];
    ushort8 o;
    for (int k = 0; k < 4; ++k) { o[k] = fcvt(a[k]); o[k + 4] = fcvt(b[k]); }
    *((ushort8*)d + i) = o;
}

// ---------------------------------------------------------------------------
// R16 GEMM core.  Tile BM(M) x BN(N), BK=32, 256 thr = 4 waves as 2x2.
// Each wave: (BM/2) x (BN/2) out via acc[BM/32][BN/32] tiles of 16x16x32.
// Staging: global_load_lds 16B/lane; one wave-load = 16 rows x 64B of
// contiguous LDS (row r lands at elem r*32); A needs BM/64 loads/wave,
// B needs BN/64.  Source chunk pre-swizzled (c ^= (row>>1)&3); read
// slot = quad ^ ((l15>>1)&3)  ->  bank start 16*(l15&1) + 4*(q^x):
// only lanes l15 / l15+8 collide = 2-way = free.
// K-loop: issue next-tile gl_lds -> ds_read+MFMA current -> one barrier.
// Residency: proj3 35KB LDS -> 3 blocks/CU (grid 768 = one round);
// gemm_out 16KB -> grid-limited 4 blocks/CU.  TLP across blocks hides
// the per-step vmcnt drain (m114).
// ---------------------------------------------------------------------------
template<int BM, int BN>
__device__ __attribute__((always_inline)) inline void gemm_core3(
    const ushort_t* __restrict__ A, const ushort_t* __restrict__ W,
    int m0, int n0, int tid, f32x4 (&acc)[BM / 32][BN / 32], ushort_t* sLDS)
{
    constexpr int TA = BM * 32;            // A tile elems
    constexpr int TB = BN * 32;            // B tile elems
    ushort_t* const aB0 = sLDS;
    ushort_t* const aB1 = sLDS + TA;
    ushort_t* const bB0 = sLDS + 2 * TA;
    ushort_t* const bB1 = sLDS + 2 * TA + TB;

    const int w    = tid >> 6;
    const int lane = tid & 63;
    const int quad = lane >> 4;
    const int l15  = lane & 15;
    const int wm   = w >> 1;
    const int wn   = w & 1;

    // staging: 4 lanes/row, 16 rows per gload; source chunk swizzled
    const int srow = lane >> 2;                        // 0..15
    const int sch  = (((lane & 3) ^ ((lane >> 3) & 3)) << 3);  // elems
    const ushort_t* Ag = A + (size_t)(m0 + w * (BM / 4) + srow) * DIM + sch;
    const ushort_t* Bg = W + (size_t)(n0 + w * (BN / 4) + srow) * DIM + sch;
    const int aOff = w * (BM / 4) * 32;    // elems
    const int bOff = w * (BN / 4) * 32;

    // prologue: stage tile 0 into buffer 0
    for (int i = 0; i < BM / 64; ++i)
        gload16(Ag + (size_t)(i * 16) * DIM, aB0 + aOff + i * 512);
    for (int i = 0; i < BN / 64; ++i)
        gload16(Bg + (size_t)(i * 16) * DIM, bB0 + bOff + i * 512);
    __syncthreads();

    const int slot = (quad ^ ((l15 >> 1) & 3)) << 3;   // read-side elem off
    for (int it = 0; it < DIM / 32; ++it) {
        const int cur = it & 1;
        ushort_t* aC = cur ? aB1 : aB0;
        ushort_t* bC = cur ? bB1 : bB0;
        ushort_t* aN = cur ? aB0 : aB1;
        ushort_t* bN = cur ? bB0 : bB1;

        if (it + 1 < DIM / 32) {
            const int k0 = (it + 1) * 32;
            for (int i = 0; i < BM / 64; ++i)
                gload16(Ag + k0 + (size_t)(i * 16) * DIM, aN + aOff + i * 512);
            for (int i = 0; i < BN / 64; ++i)
                gload16(Bg + k0 + (size_t)(i * 16) * DIM, bN + bOff + i * 512);
        }

        bf16x8 af[BM / 32], bf[BN / 32];
        for (int i = 0; i < BM / 32; ++i) {
            int row = wm * (BM / 2) + i * 16 + l15;
            af[i] = lds_frag(aC + row * 32 + slot);
        }
        for (int j = 0; j < BN / 32; ++j) {
            int row = wn * (BN / 2) + j * 16 + l15;
            bf[j] = lds_frag(bC + row * 32 + slot);
        }
        for (int i = 0; i < BM / 32; ++i)
            for (int j = 0; j < BN / 32; ++j)
                acc[i][j] = __builtin_amdgcn_mfma_f32_16x16x32_bf16(
                    af[i], bf[j], acc[i][j], 0, 0, 0);
        __syncthreads();
    }
}

// Fused Q/K/V projections: z = 0 (Q, scaled), 1 (K), 2 (V, transposed out).
// grid = (DIM/128, SEQ/128, 3) = (8, 32, 3) = 768 blocks; 35KB LDS ->
// 3 blocks/CU -> exactly one residency round.
__global__ __launch_bounds__(256, 3) void proj3(
    const ushort_t* __restrict__ Qb, const ushort_t* __restrict__ KVb,
    const ushort_t* __restrict__ qwb, const ushort_t* __restrict__ kwb,
    const ushort_t* __restrict__ vwb,
    const float* __restrict__ q_b, const float* __restrict__ k_b,
    const float* __restrict__ v_b,
    ushort_t* __restrict__ Qp, ushort_t* __restrict__ Kp,
    ushort_t* __restrict__ VpT)
{
    // 16384 elems for GEMM buffers; 17536 for the V^T transpose epilogue
    __shared__ __align__(1024) ushort_t sLDS[17536];   // 35072 B

    const int z = blockIdx.z;
    const ushort_t* A = z ? KVb : Qb;
    const ushort_t* W = (z == 0) ? qwb : (z == 1 ? kwb : vwb);
    const float* bias = (z == 0) ? q_b : (z == 1 ? k_b : v_b);
    const int tid = threadIdx.x;
    const int m0 = blockIdx.y * 128;
    const int n0 = blockIdx.x * 128;

    f32x4 acc[4][4] = {};
    gemm_core3<128, 128>(A, W, m0, n0, tid, acc, sLDS);

    const int lane = tid & 63, quad = lane >> 4, l15 = lane & 15;
    const int wm = (tid >> 6) >> 1, wn = (tid >> 6) & 1;

    if (z == 2) {
        // V^T epilogue: transpose 128x128 C-tile through LDS (free after
        // gemm_core3's final barrier), then coalesced stores.
        const int TSTR = 136;                // row stride: 272B, 16B-aligned
        for (int j = 0; j < 4; ++j) {
            int col = wn * 64 + j * 16 + l15;           // tile-local n
            float bj = bias[n0 + col];
            for (int i = 0; i < 4; ++i) {
                int row = wm * 64 + i * 16 + quad * 4;  // tile-local m
                ushort4v o4;
                for (int r = 0; r < 4; ++r) o4[r] = fcvt(acc[i][j][r] + bj);
                *(ushort4v*)(sLDS + col * TSTR + row) = o4;
            }
        }
        __syncthreads();
        const int vrow = tid >> 1;           // 0..127  (V^T row = tile col)
        const int vc   = (tid & 1) * 64;
        ushort_t* dst = VpT + (size_t)(n0 + vrow) * SEQ + m0 + vc;
        const ushort_t* src = sLDS + vrow * TSTR + vc;
        for (int k = 0; k < 8; ++k)
            *(ushort8*)(dst + k * 8) = *(const ushort8*)(src + k * 8);
    } else {
        const float scale = (z == 0) ? QSCALE : 1.0f;
        ushort_t* C = z ? Kp : Qp;
        for (int j = 0; j < 4; ++j) {
            int col = n0 + wn * 64 + j * 16 + l15;
            float bj = bias[col];
            for (int i = 0; i < 4; ++i) {
                int row = m0 + wm * 64 + i * 16 + quad * 4;
                for (int r = 0; r < 4; ++r)
                    C[(size_t)(row + r) * DIM + col] =
                        fcvt((acc[i][j][r] + bj) * scale);
            }
        }
    }
}

// O projection: f32 output.  64x64 tile, BK=32, 16KB LDS.
// grid = (DIM/64, SEQ/64) = (16, 64) = 1024 blocks -> 4 blocks/CU.
__global__ __launch_bounds__(256, 4) void gemm_out(
    const ushort_t* __restrict__ A, const ushort_t* __restrict__ W,
    const float* __restrict__ bias, float* __restrict__ C)
{
    __shared__ __align__(1024) ushort_t sLDS[8192];    // 16 KB

    const int tid = threadIdx.x;
    const int m0 = blockIdx.y * 64;
    const int n0 = blockIdx.x * 64;

    f32x4 acc[2][2] = {};
    gemm_core3<64, 64>(A, W, m0, n0, tid, acc, sLDS);

    const int lane = tid & 63, quad = lane >> 4, l15 = lane & 15;
    const int wm = (tid >> 6) >> 1, wn = (tid >> 6) & 1;
    for (int j = 0; j < 2; ++j) {
        int col = n0 + wn * 32 + j * 16 + l15;
        float bj = bias[col];
        for (int i = 0; i < 2; ++i) {
            int row = m0 + wm * 32 + i * 16 + quad * 4;
            for (int r = 0; r < 4; ++r)
                C[(size_t)(row + r) * DIM + col] = acc[i][j][r] + bj;
        }
    }
}

// ---------------------------------------------------------------------------
// Flash attention.  As R15, plus: softmax denominator accumulated on the
// MFMA pipe (l_acc = mfma(ones, pf, l_acc)) instead of 32 f32 adds + shfl
// per iter on the critical VALU pipe.  l_i = row-sum of P lands at
// lane l31 (q index), reg 0.
// grid = (NH, SEQ/128) = (16, 32), 256 thr = 4 waves x 32 q rows.
// ---------------------------------------------------------------------------
#define TILE 4096                  // elems per 64x64 bf16 tile
#define BUFE (2 * TILE)            // K tile + V tile per buffer
__global__ __launch_bounds__(256, 2) void attn_kernel(
    const ushort_t* __restrict__ Q, const ushort_t* __restrict__ K,
    const ushort_t* __restrict__ VT, ushort_t* __restrict__ O)
{
    __shared__ __align__(16) ushort_t sB[2 * BUFE];   // 32768 B

    const int tid  = threadIdx.x;
    const int w    = tid >> 6;
    const int lane = tid & 63;
    const int l31  = lane & 31;
    const int hi   = lane >> 5;
    const int h    = blockIdx.x;
    const int q0   = blockIdx.y * 128 + w * 32;
    const int hHD  = h * HD;

    const int srow0 = tid >> 3;
    const int srow1 = srow0 + 32;
    const int sch   = (tid & 7) << 3;
    const ushort_t* Kg0 = K  + (size_t)srow0 * DIM + hHD + sch;
    const ushort_t* Kg1 = K  + (size_t)srow1 * DIM + hHD + sch;
    const ushort_t* Vg0 = VT + (size_t)(hHD + srow0) * SEQ + sch;
    const ushort_t* Vg1 = VT + (size_t)(hHD + srow1) * SEQ + sch;
    const int lk0 = swz(srow0, sch), lk1 = swz(srow1, sch);

    const ushort_t* qb = Q + (size_t)(q0 + l31) * DIM + hHD + hi * 8;
    bf16x8 qf[4];
    for (int ks = 0; ks < 4; ++ks)
        qf[ks] = frag_of(*(const ushort8*)(qb + ks * 16));

    bf16x8 onef;
    for (int i = 0; i < 8; ++i) onef[i] = (__bf16)1.0f;

    *(ushort8*)(sB + lk0)        = *(const ushort8*)(Kg0);
    *(ushort8*)(sB + lk1)        = *(const ushort8*)(Kg1);
    *(ushort8*)(sB + TILE + lk0) = *(const ushort8*)(Vg0);
    *(ushort8*)(sB + TILE + lk1) = *(const ushort8*)(Vg1);
    __syncthreads();

    f32x16 oacc[2] = {};
    f32x16 lacc = {};

    for (int it = 0; it < SEQ / 64; ++it) {
        const int cur = it & 1;
        const int kvn = (it + 1) * 64;
        ushort_t* bK = sB + cur * BUFE;
        ushort_t* bV = bK + TILE;

        ushort8 gk0, gk1, gv0, gv1;
        if (kvn < SEQ) {
            gk0 = *(const ushort8*)(Kg0 + (size_t)kvn * DIM);
            gk1 = *(const ushort8*)(Kg1 + (size_t)kvn * DIM);
            gv0 = *(const ushort8*)(Vg0 + kvn);
            gv1 = *(const ushort8*)(Vg1 + kvn);
        }

        bf16x8 kf[8], vf[8];
        for (int t = 0; t < 2; ++t)
            for (int ks = 0; ks < 4; ++ks) {
                int r = t * 32 + l31;
                kf[t * 4 + ks] = lds_frag(bK + swz(r, ks * 16 + hi * 8));
            }
        for (int dt = 0; dt < 2; ++dt)
            for (int ks = 0; ks < 4; ++ks) {
                int r = dt * 32 + l31;
                vf[ks * 2 + dt] = lds_frag(bV + swz(r, ks * 16 + hi * 8));
            }

        // S^T = K Q^T : lane l31 = q col, regs = kv rows
        f32x16 sacc[2] = {};
        for (int t = 0; t < 2; ++t)
            for (int ks = 0; ks < 4; ++ks)
                sacc[t] = __builtin_amdgcn_mfma_f32_32x32x16_bf16(
                    kf[t * 4 + ks], qf[ks], sacc[t], 0, 0, 0);

        for (int t = 0; t < 2; ++t)
            for (int r = 0; r < 16; ++r)
                sacc[t][r] = __builtin_amdgcn_exp2f(sacc[t][r]);

        // In-register P -> PV B-fragment (see R13 derivation); the
        // denominator rides the MFMA pipe via the ones-matrix product.
        for (int ks = 0; ks < 4; ++ks) {
            const int t = ks >> 1, s8 = (ks & 1) * 8;
            unsigned p00 = pk2(sacc[t][s8 + 0], sacc[t][s8 + 1]);
            unsigned p01 = pk2(sacc[t][s8 + 2], sacc[t][s8 + 3]);
            unsigned p10 = pk2(sacc[t][s8 + 4], sacc[t][s8 + 5]);
            unsigned p11 = pk2(sacc[t][s8 + 6], sacc[t][s8 + 7]);
            plswap(p00, p10);
            plswap(p01, p11);
            uint4v wv; wv[0] = p00; wv[1] = p01; wv[2] = p10; wv[3] = p11;
            bf16x8 pf = __builtin_bit_cast(bf16x8, wv);
            for (int dt = 0; dt < 2; ++dt)
                oacc[dt] = __builtin_amdgcn_mfma_f32_32x32x16_bf16(
                    vf[ks * 2 + dt], pf, oacc[dt], 0, 0, 0);
            lacc = __builtin_amdgcn_mfma_f32_32x32x16_bf16(
                onef, pf, lacc, 0, 0, 0);
        }

        if (kvn < SEQ) {
            ushort_t* nB = sB + (cur ^ 1) * BUFE;
            *(ushort8*)(nB + lk0)        = gk0;
            *(ushort8*)(nB + lk1)        = gk1;
            *(ushort8*)(nB + TILE + lk0) = gv0;
            *(ushort8*)(nB + TILE + lk1) = gv1;
        }
        __syncthreads();
    }

    float inv = 1.f / lacc[0];
    int qrow = q0 + l31;
    for (int dt = 0; dt < 2; ++dt)
        for (int g = 0; g < 4; ++g) {
            ushort4v o4;
            for (int r = 0; r < 4; ++r) o4[r] = fcvt(oacc[dt][g * 4 + r] * inv);
            *(ushort4v*)(O + (size_t)qrow * DIM + hHD + dt * 32 + g * 8 + hi * 4) = o4;
        }
}

// ---------------------------------------------------------------------------
extern "C" void kernel_launch(void* const* d_in, const int* in_sizes, int n_in,
                              void* d_out, int out_size, void* d_ws, size_t ws_size,
                              hipStream_t stream)
{
    const float* q   = (const float*)d_in[0];
    const float* kv  = (const float*)d_in[1];
    const float* q_w = (const float*)d_in[2];
    const float* q_b = (const float*)d_in[3];
    const float* k_w = (const float*)d_in[4];
    const float* k_b = (const float*)d_in[5];
    const float* v_w = (const float*)d_in[6];
    const float* v_b = (const float*)d_in[7];
    const float* o_w = (const float*)d_in[8];
    const float* o_b = (const float*)d_in[9];
    float* out = (float*)d_out;

    const size_t SD = (size_t)SEQ * DIM;
    const size_t WW = (size_t)DIM * DIM;
    ushort_t* Qp  = (ushort_t*)d_ws;          // bf16, pre-scaled by QSCALE
    ushort_t* Kp  = Qp + SD;
    ushort_t* VpT = Kp + SD;                  // V^T: [DIM][SEQ]
    ushort_t* AO  = VpT + SD;                 // attention out; aliases Qb
    ushort_t* Qb  = AO;                       // bf16(q) — dead before AO write
    ushort_t* KVb = AO + SD;
    ushort_t* qwb = KVb + SD;
    ushort_t* kwb = qwb + WW;
    ushort_t* vwb = kwb + WW;
    ushort_t* owb = vwb + WW;

    cvt2<<<dim3((unsigned)(SD / 8 / 256), 2), 256, 0, stream>>>(
        q, Qb, kv, KVb, (int)(SD / 8));
    cvt4<<<dim3((unsigned)(WW / 8 / 256), 4), 256, 0, stream>>>(
        q_w, qwb, k_w, kwb, v_w, vwb, o_w, owb, (int)(WW / 8));

    proj3<<<dim3(DIM / 128, SEQ / 128, 3), 256, 0, stream>>>(
        Qb, KVb, qwb, kwb, vwb, q_b, k_b, v_b, Qp, Kp, VpT);
    attn_kernel<<<dim3(NH, SEQ / 128), 256, 0, stream>>>(Qp, Kp, VpT, AO);
    gemm_out<<<dim3(DIM / 64, SEQ / 64), 256, 0, stream>>>(AO, owb, o_b, out);
}

// Round 8
// 245.723 us; speedup vs baseline: 1.0051x; 1.0051x over previous
//
#include <hip/hip_runtime.h>

// ---------------------------------------------------------------------------
// MHA forward, fp32 I/O.  S=4096, D=1024, NH=16, HD=64.
// R20: green revert + XCD locality.  R17-R19 all failed (~1.3e-2) on attn
// rewrites; attn reverted to the R15 body (green twice, 97.5us).  New:
// XCD-aware chunked blockIdx swizzle (T1) on proj3/gemm_out/attn.  HW maps
// consecutive blocks round-robin across 8 XCDs, so blocks sharing an
// A-panel / weight matrix / head-KV were L2-scattered: proj3's aggregate
// demand ~384MB (~4.1TB/s) -> duplication-bound (explains why R14-R16
// K-loop restructures were all null).  Remap bid -> (bid&7)*(nwg/8) +
// (bid>>3) (bijective, nwg%8==0: 768/1024/512) so each XCD owns a
// contiguous tile chunk: per-XCD set proj3 ~5MB / gemm_out 3MB / attn
// 2-heads 3MB -> L2-resident.  Zero math change anywhere.
// ---------------------------------------------------------------------------

typedef unsigned short ushort_t;
typedef unsigned short ushort4v __attribute__((ext_vector_type(4)));
typedef unsigned short ushort8 __attribute__((ext_vector_type(8)));
typedef __bf16 bf16x8 __attribute__((ext_vector_type(8)));
typedef float f32x4 __attribute__((ext_vector_type(4)));
typedef float f32x16 __attribute__((ext_vector_type(16)));
typedef unsigned int uint4v __attribute__((ext_vector_type(4)));

#define SEQ 4096
#define DIM 1024
#define NH 16
#define HD 64
// 0.125 * log2(e): folded into Q projection so softmax uses exp2 directly
#define QSCALE 0.18033688011112042f

__device__ inline ushort_t fcvt(float f) {           // native f32->bf16 RTNE
    return __builtin_bit_cast(ushort_t, (__bf16)f);
}
__device__ inline bf16x8 frag_of(ushort8 t) {
    return __builtin_bit_cast(bf16x8, t);
}
__device__ inline bf16x8 lds_frag(const ushort_t* p) {
    return frag_of(*(const ushort8*)p);
}
__device__ inline unsigned pk2(float a, float b) {   // packed bf16 pair
    return (unsigned)fcvt(a) | ((unsigned)fcvt(b) << 16);
}
// swap lanes 32-63 of a with lanes 0-31 of b (gfx950 cross-lane op)
__device__ inline void plswap(unsigned& a, unsigned& b) {
    asm("v_permlane32_swap_b32 %0, %1" : "+v"(a), "+v"(b));
}
// swizzled elem offset within a linear [64][64] bf16 LDS tile (attn)
__device__ inline int swz(int row, int col) {
    return row * 64 + (col ^ ((row & 7) << 3));
}
// XCD-aware chunked remap: HW sends consecutive blocks round-robin to the
// 8 XCDs; this makes XCD k own logical tiles [k*nwg/8, (k+1)*nwg/8).
// Bijective when nwg % 8 == 0 (all our grids: 768 / 1024 / 512).
__device__ inline int xcd_swz(int bid, int nwg) {
    return (bid & 7) * (nwg >> 3) + (bid >> 3);
}
// async global->LDS, 16B per lane; LDS dest = wave-uniform base + lane*16
__device__ __attribute__((always_inline)) inline void gload16(
    const ushort_t* g, ushort_t* l)
{
    __builtin_amdgcn_global_load_lds(
        (const __attribute__((address_space(1))) void*)g,
        (__attribute__((address_space(3))) void*)l, 16, 0, 0);
}

// ---------------------------------------------------------------------------
// Prep: f32 -> bf16 converts (R16-exact)
// ---------------------------------------------------------------------------
__global__ __launch_bounds__(256) void cvt2(
    const float* __restrict__ s0, ushort_t* __restrict__ d0,
    const float* __restrict__ s1, ushort_t* __restrict__ d1, int n8)
{
    const float* s = blockIdx.y ? s1 : s0;
    ushort_t*    d = blockIdx.y ? d1 : d0;
    int i = blockIdx.x * 256 + threadIdx.x;
    if (i >= n8) return;
    const f32x4* sp = (const f32x4*)s + (size_t)i * 2;
    f32x4 a = sp[0], b = sp[1];
    ushort8 o;
    for (int k = 0; k < 4; ++k) { o[k] = fcvt(a[k]); o[k + 4] = fcvt(b[k]); }
    *((ushort8*)d + i) = o;
}

__global__ __launch_bounds__(256) void cvt4(
    const float* __restrict__ s0, ushort_t* __restrict__ d0,
    const float* __restrict__ s1, ushort_t* __restrict__ d1,
    const float* __restrict__ s2, ushort_t* __restrict__ d2,
    const float* __restrict__ s3, ushort_t* __restrict__ d3, int n8)
{
    const float* ss[4] = {s0, s1, s2, s3};
    ushort_t*    dd[4] = {d0, d1, d2, d3};
    const float* s = ss[blockIdx.y];
    ushort_t*    d = dd[blockIdx.y];
    int i = blockIdx.x * 256 + threadIdx.x;
    if (i >= n8) return;
    const f32x4* sp = (const f32x4*)s + (size_t)i * 2;
    f32x4 a = sp[0], b = sp[1];
    ushort8 o;
    for (int k = 0; k < 4; ++k) { o[k] = fcvt(a[k]); o[k + 4] = fcvt(b[k]); }
    *((ushort8*)d + i) = o;
}

// ---------------------------------------------------------------------------
// GEMM core (R16-exact).  Tile BM x BN, BK=32, 4 waves 2x2.
// global_load_lds 16B staging, source-chunk swizzle, 1 barrier/K-step.
// ---------------------------------------------------------------------------
template<int BM, int BN>
__device__ __attribute__((always_inline)) inline void gemm_core3(
    const ushort_t* __restrict__ A, const ushort_t* __restrict__ W,
    int m0, int n0, int tid, f32x4 (&acc)[BM / 32][BN / 32], ushort_t* sLDS)
{
    constexpr int TA = BM * 32;            // A tile elems
    constexpr int TB = BN * 32;            // B tile elems
    ushort_t* const aB0 = sLDS;
    ushort_t* const aB1 = sLDS + TA;
    ushort_t* const bB0 = sLDS + 2 * TA;
    ushort_t* const bB1 = sLDS + 2 * TA + TB;

    const int w    = tid >> 6;
    const int lane = tid & 63;
    const int quad = lane >> 4;
    const int l15  = lane & 15;
    const int wm   = w >> 1;
    const int wn   = w & 1;

    // staging: 4 lanes/row, 16 rows per gload; source chunk swizzled
    const int srow = lane >> 2;                        // 0..15
    const int sch  = (((lane & 3) ^ ((lane >> 3) & 3)) << 3);  // elems
    const ushort_t* Ag = A + (size_t)(m0 + w * (BM / 4) + srow) * DIM + sch;
    const ushort_t* Bg = W + (size_t)(n0 + w * (BN / 4) + srow) * DIM + sch;
    const int aOff = w * (BM / 4) * 32;    // elems
    const int bOff = w * (BN / 4) * 32;

    // prologue: stage tile 0 into buffer 0
    for (int i = 0; i < BM / 64; ++i)
        gload16(Ag + (size_t)(i * 16) * DIM, aB0 + aOff + i * 512);
    for (int i = 0; i < BN / 64; ++i)
        gload16(Bg + (size_t)(i * 16) * DIM, bB0 + bOff + i * 512);
    __syncthreads();

    const int slot = (quad ^ ((l15 >> 1) & 3)) << 3;   // read-side elem off
    for (int it = 0; it < DIM / 32; ++it) {
        const int cur = it & 1;
        ushort_t* aC = cur ? aB1 : aB0;
        ushort_t* bC = cur ? bB1 : bB0;
        ushort_t* aN = cur ? aB0 : aB1;
        ushort_t* bN = cur ? bB0 : bB1;

        if (it + 1 < DIM / 32) {
            const int k0 = (it + 1) * 32;
            for (int i = 0; i < BM / 64; ++i)
                gload16(Ag + k0 + (size_t)(i * 16) * DIM, aN + aOff + i * 512);
            for (int i = 0; i < BN / 64; ++i)
                gload16(Bg + k0 + (size_t)(i * 16) * DIM, bN + bOff + i * 512);
        }

        bf16x8 af[BM / 32], bf[BN / 32];
        for (int i = 0; i < BM / 32; ++i) {
            int row = wm * (BM / 2) + i * 16 + l15;
            af[i] = lds_frag(aC + row * 32 + slot);
        }
        for (int j = 0; j < BN / 32; ++j) {
            int row = wn * (BN / 2) + j * 16 + l15;
            bf[j] = lds_frag(bC + row * 32 + slot);
        }
        for (int i = 0; i < BM / 32; ++i)
            for (int j = 0; j < BN / 32; ++j)
                acc[i][j] = __builtin_amdgcn_mfma_f32_16x16x32_bf16(
                    af[i], bf[j], acc[i][j], 0, 0, 0);
        __syncthreads();
    }
}

// Fused Q/K/V projections: z = 0 (Q, scaled), 1 (K), 2 (V, transposed out).
// 1D grid 768, XCD-swizzled; logical tile = z*256 + my*8 + nx.
__global__ __launch_bounds__(256, 3) void proj3(
    const ushort_t* __restrict__ Qb, const ushort_t* __restrict__ KVb,
    const ushort_t* __restrict__ qwb, const ushort_t* __restrict__ kwb,
    const ushort_t* __restrict__ vwb,
    const float* __restrict__ q_b, const float* __restrict__ k_b,
    const float* __restrict__ v_b,
    ushort_t* __restrict__ Qp, ushort_t* __restrict__ Kp,
    ushort_t* __restrict__ VpT)
{
    __shared__ __align__(1024) ushort_t sLDS[17536];   // 35072 B

    const int lb = xcd_swz(blockIdx.x, 768);
    const int z  = lb >> 8;                // 0..2
    const int r  = lb & 255;
    const int m0 = (r >> 3) * 128;
    const int n0 = (r & 7) * 128;

    const ushort_t* A = z ? KVb : Qb;
    const ushort_t* W = (z == 0) ? qwb : (z == 1 ? kwb : vwb);
    const float* bias = (z == 0) ? q_b : (z == 1 ? k_b : v_b);
    const int tid = threadIdx.x;

    f32x4 acc[4][4] = {};
    gemm_core3<128, 128>(A, W, m0, n0, tid, acc, sLDS);

    const int lane = tid & 63, quad = lane >> 4, l15 = lane & 15;
    const int wm = (tid >> 6) >> 1, wn = (tid >> 6) & 1;

    if (z == 2) {
        // V^T epilogue: transpose 128x128 C-tile through LDS, coalesced out.
        const int TSTR = 136;                // row stride: 272B, 16B-aligned
        for (int j = 0; j < 4; ++j) {
            int col = wn * 64 + j * 16 + l15;           // tile-local n
            float bj = bias[n0 + col];
            for (int i = 0; i < 4; ++i) {
                int row = wm * 64 + i * 16 + quad * 4;  // tile-local m
                ushort4v o4;
                for (int r2 = 0; r2 < 4; ++r2) o4[r2] = fcvt(acc[i][j][r2] + bj);
                *(ushort4v*)(sLDS + col * TSTR + row) = o4;
            }
        }
        __syncthreads();
        const int vrow = tid >> 1;           // 0..127  (V^T row = tile col)
        const int vc   = (tid & 1) * 64;
        ushort_t* dst = VpT + (size_t)(n0 + vrow) * SEQ + m0 + vc;
        const ushort_t* src = sLDS + vrow * TSTR + vc;
        for (int k = 0; k < 8; ++k)
            *(ushort8*)(dst + k * 8) = *(const ushort8*)(src + k * 8);
    } else {
        const float scale = (z == 0) ? QSCALE : 1.0f;
        ushort_t* C = z ? Kp : Qp;
        for (int j = 0; j < 4; ++j) {
            int col = n0 + wn * 64 + j * 16 + l15;
            float bj = bias[col];
            for (int i = 0; i < 4; ++i) {
                int row = m0 + wm * 64 + i * 16 + quad * 4;
                for (int r2 = 0; r2 < 4; ++r2)
                    C[(size_t)(row + r2) * DIM + col] =
                        fcvt((acc[i][j][r2] + bj) * scale);
            }
        }
    }
}

// O projection: f32 output.  64x64 tile, BK=32, 16KB LDS.
// 1D grid 1024, XCD-swizzled; logical tile = my*16 + nx (m-major).
__global__ __launch_bounds__(256, 4) void gemm_out(
    const ushort_t* __restrict__ A, const ushort_t* __restrict__ W,
    const float* __restrict__ bias, float* __restrict__ C)
{
    __shared__ __align__(1024) ushort_t sLDS[8192];    // 16 KB

    const int lb = xcd_swz(blockIdx.x, 1024);
    const int m0 = (lb >> 4) * 64;
    const int n0 = (lb & 15) * 64;
    const int tid = threadIdx.x;

    f32x4 acc[2][2] = {};
    gemm_core3<64, 64>(A, W, m0, n0, tid, acc, sLDS);

    const int lane = tid & 63, quad = lane >> 4, l15 = lane & 15;
    const int wm = (tid >> 6) >> 1, wn = (tid >> 6) & 1;
    for (int j = 0; j < 2; ++j) {
        int col = n0 + wn * 32 + j * 16 + l15;
        float bj = bias[col];
        for (int i = 0; i < 2; ++i) {
            int row = m0 + wm * 32 + i * 16 + quad * 4;
            for (int r = 0; r < 4; ++r)
                C[(size_t)(row + r) * DIM + col] = acc[i][j][r] + bj;
        }
    }
}

// ---------------------------------------------------------------------------
// Flash attention — R15 body (green twice), 1D grid + XCD swizzle only.
// 256 thr = 4 waves x 32 q rows, full KV sweep, swapped QK^T, zero-shift
// exp2 softmax, P-in-register via pk2+permlane32_swap, XOR-swizzled K/V
// tiles, register-prefetch double-buffer, 1 barrier/iter.
// 1D grid 512, logical = h*32 + qblk -> each XCD owns 2 heads (K/V/Q
// slices ~3MB, L2-resident).
// ---------------------------------------------------------------------------
#define TILE 4096                  // elems per 64x64 bf16 tile
#define BUFE (2 * TILE)            // K tile + V tile per buffer
__global__ __launch_bounds__(256, 2) void attn_kernel(
    const ushort_t* __restrict__ Q, const ushort_t* __restrict__ K,
    const ushort_t* __restrict__ VT, ushort_t* __restrict__ O)
{
    __shared__ __align__(16) ushort_t sB[2 * BUFE];   // 32768 B

    const int lb   = xcd_swz(blockIdx.x, 512);
    const int h    = lb >> 5;
    const int qblk = lb & 31;

    const int tid  = threadIdx.x;
    const int w    = tid >> 6;
    const int lane = tid & 63;
    const int l31  = lane & 31;
    const int hi   = lane >> 5;
    const int q0   = qblk * 128 + w * 32;
    const int hHD  = h * HD;

    const int srow0 = tid >> 3;
    const int srow1 = srow0 + 32;
    const int sch   = (tid & 7) << 3;
    const ushort_t* Kg0 = K  + (size_t)srow0 * DIM + hHD + sch;
    const ushort_t* Kg1 = K  + (size_t)srow1 * DIM + hHD + sch;
    const ushort_t* Vg0 = VT + (size_t)(hHD + srow0) * SEQ + sch;
    const ushort_t* Vg1 = VT + (size_t)(hHD + srow1) * SEQ + sch;
    const int lk0 = swz(srow0, sch), lk1 = swz(srow1, sch);

    const ushort_t* qb = Q + (size_t)(q0 + l31) * DIM + hHD + hi * 8;
    bf16x8 qf[4];
    for (int ks = 0; ks < 4; ++ks)
        qf[ks] = frag_of(*(const ushort8*)(qb + ks * 16));

    *(ushort8*)(sB + lk0)        = *(const ushort8*)(Kg0);
    *(ushort8*)(sB + lk1)        = *(const ushort8*)(Kg1);
    *(ushort8*)(sB + TILE + lk0) = *(const ushort8*)(Vg0);
    *(ushort8*)(sB + TILE + lk1) = *(const ushort8*)(Vg1);
    __syncthreads();

    f32x16 oacc[2] = {};
    float l_i = 0.f;

    for (int it = 0; it < SEQ / 64; ++it) {
        const int cur = it & 1;
        const int kvn = (it + 1) * 64;
        ushort_t* bK = sB + cur * BUFE;
        ushort_t* bV = bK + TILE;

        ushort8 gk0, gk1, gv0, gv1;
        if (kvn < SEQ) {
            gk0 = *(const ushort8*)(Kg0 + (size_t)kvn * DIM);
            gk1 = *(const ushort8*)(Kg1 + (size_t)kvn * DIM);
            gv0 = *(const ushort8*)(Vg0 + kvn);
            gv1 = *(const ushort8*)(Vg1 + kvn);
        }

        bf16x8 kf[8], vf[8];
        for (int t = 0; t < 2; ++t)
            for (int ks = 0; ks < 4; ++ks) {
                int r = t * 32 + l31;
                kf[t * 4 + ks] = lds_frag(bK + swz(r, ks * 16 + hi * 8));
            }
        for (int dt = 0; dt < 2; ++dt)
            for (int ks = 0; ks < 4; ++ks) {
                int r = dt * 32 + l31;
                vf[ks * 2 + dt] = lds_frag(bV + swz(r, ks * 16 + hi * 8));
            }

        // S^T = K Q^T : lane l31 = q col, regs = kv rows
        f32x16 sacc[2] = {};
        for (int t = 0; t < 2; ++t)
            for (int ks = 0; ks < 4; ++ks)
                sacc[t] = __builtin_amdgcn_mfma_f32_32x32x16_bf16(
                    kf[t * 4 + ks], qf[ks], sacc[t], 0, 0, 0);

        float lp = 0.f;
        for (int t = 0; t < 2; ++t)
            for (int r = 0; r < 16; ++r) {
                float p = __builtin_amdgcn_exp2f(sacc[t][r]);
                sacc[t][r] = p;
                lp += p;
            }
        l_i += lp + __shfl_xor(lp, 32);

        // In-register P -> PV B-fragment (see R13 derivation).
        for (int ks = 0; ks < 4; ++ks) {
            const int t = ks >> 1, s8 = (ks & 1) * 8;
            unsigned p00 = pk2(sacc[t][s8 + 0], sacc[t][s8 + 1]);
            unsigned p01 = pk2(sacc[t][s8 + 2], sacc[t][s8 + 3]);
            unsigned p10 = pk2(sacc[t][s8 + 4], sacc[t][s8 + 5]);
            unsigned p11 = pk2(sacc[t][s8 + 6], sacc[t][s8 + 7]);
            plswap(p00, p10);
            plswap(p01, p11);
            uint4v wv; wv[0] = p00; wv[1] = p01; wv[2] = p10; wv[3] = p11;
            bf16x8 pf = __builtin_bit_cast(bf16x8, wv);
            for (int dt = 0; dt < 2; ++dt)
                oacc[dt] = __builtin_amdgcn_mfma_f32_32x32x16_bf16(
                    vf[ks * 2 + dt], pf, oacc[dt], 0, 0, 0);
        }

        if (kvn < SEQ) {
            ushort_t* nB = sB + (cur ^ 1) * BUFE;
            *(ushort8*)(nB + lk0)        = gk0;
            *(ushort8*)(nB + lk1)        = gk1;
            *(ushort8*)(nB + TILE + lk0) = gv0;
            *(ushort8*)(nB + TILE + lk1) = gv1;
        }
        __syncthreads();
    }

    float inv = 1.f / l_i;
    int qrow = q0 + l31;
    for (int dt = 0; dt < 2; ++dt)
        for (int g = 0; g < 4; ++g) {
            ushort4v o4;
            for (int r = 0; r < 4; ++r) o4[r] = fcvt(oacc[dt][g * 4 + r] * inv);
            *(ushort4v*)(O + (size_t)qrow * DIM + hHD + dt * 32 + g * 8 + hi * 4) = o4;
        }
}

// ---------------------------------------------------------------------------
extern "C" void kernel_launch(void* const* d_in, const int* in_sizes, int n_in,
                              void* d_out, int out_size, void* d_ws, size_t ws_size,
                              hipStream_t stream)
{
    const float* q   = (const float*)d_in[0];
    const float* kv  = (const float*)d_in[1];
    const float* q_w = (const float*)d_in[2];
    const float* q_b = (const float*)d_in[3];
    const float* k_w = (const float*)d_in[4];
    const float* k_b = (const float*)d_in[5];
    const float* v_w = (const float*)d_in[6];
    const float* v_b = (const float*)d_in[7];
    const float* o_w = (const float*)d_in[8];
    const float* o_b = (const float*)d_in[9];
    float* out = (float*)d_out;

    const size_t SD = (size_t)SEQ * DIM;
    const size_t WW = (size_t)DIM * DIM;
    ushort_t* Qp  = (ushort_t*)d_ws;          // bf16, pre-scaled by QSCALE
    ushort_t* Kp  = Qp + SD;
    ushort_t* VpT = Kp + SD;                  // V^T: [DIM][SEQ]
    ushort_t* AO  = VpT + SD;                 // attention out; aliases Qb
    ushort_t* Qb  = AO;                       // bf16(q) — dead before AO write
    ushort_t* KVb = AO + SD;
    ushort_t* qwb = KVb + SD;
    ushort_t* kwb = qwb + WW;
    ushort_t* vwb = kwb + WW;
    ushort_t* owb = vwb + WW;

    cvt2<<<dim3((unsigned)(SD / 8 / 256), 2), 256, 0, stream>>>(
        q, Qb, kv, KVb, (int)(SD / 8));
    cvt4<<<dim3((unsigned)(WW / 8 / 256), 4), 256, 0, stream>>>(
        q_w, qwb, k_w, kwb, v_w, vwb, o_w, owb, (int)(WW / 8));

    proj3<<<dim3(768), 256, 0, stream>>>(
        Qb, KVb, qwb, kwb, vwb, q_b, k_b, v_b, Qp, Kp, VpT);
    attn_kernel<<<dim3(512), 256, 0, stream>>>(Qp, Kp, VpT, AO);
    gemm_out<<<dim3(1024), 256, 0, stream>>>(AO, owb, o_b, out);
}

// Round 9
// 242.172 us; speedup vs baseline: 1.0198x; 1.0147x over previous
//
#include <hip/hip_runtime.h>

// ---------------------------------------------------------------------------
// MHA forward, fp32 I/O.  S=4096, D=1024, NH=16, HD=64.
// R21: attn T15 software pipeline.  attn is latency-bound on the serial
// per-iter chain QK->exp2->pack->PV with only 2 waves/SIMD (grid-capped;
// both split attempts carried an unexplained deterministic defect and are
// abandoned).  PV(it-1) is deferred into iter it: it issues independent
// MFMA work under QK(it)'s latency and exp2(it)'s VALU time.  P(prev) and
// V(prev) are carried in registers; V's ds_read moves after the PV that
// consumes the old V (register reuse + latency covered by the iter tail).
// FP accumulation order is UNCHANGED (PV lands in oacc in order 0..63;
// l_i order identical) -> output must be bit-identical to R20.
// Everything except attn_kernel is byte-identical to R20 (green, 245.7us;
// XCD swizzle kept: null but harmless).
// ---------------------------------------------------------------------------

typedef unsigned short ushort_t;
typedef unsigned short ushort4v __attribute__((ext_vector_type(4)));
typedef unsigned short ushort8 __attribute__((ext_vector_type(8)));
typedef __bf16 bf16x8 __attribute__((ext_vector_type(8)));
typedef float f32x4 __attribute__((ext_vector_type(4)));
typedef float f32x16 __attribute__((ext_vector_type(16)));
typedef unsigned int uint4v __attribute__((ext_vector_type(4)));

#define SEQ 4096
#define DIM 1024
#define NH 16
#define HD 64
// 0.125 * log2(e): folded into Q projection so softmax uses exp2 directly
#define QSCALE 0.18033688011112042f

__device__ inline ushort_t fcvt(float f) {           // native f32->bf16 RTNE
    return __builtin_bit_cast(ushort_t, (__bf16)f);
}
__device__ inline bf16x8 frag_of(ushort8 t) {
    return __builtin_bit_cast(bf16x8, t);
}
__device__ inline bf16x8 lds_frag(const ushort_t* p) {
    return frag_of(*(const ushort8*)p);
}
__device__ inline unsigned pk2(float a, float b) {   // packed bf16 pair
    return (unsigned)fcvt(a) | ((unsigned)fcvt(b) << 16);
}
// swap lanes 32-63 of a with lanes 0-31 of b (gfx950 cross-lane op)
__device__ inline void plswap(unsigned& a, unsigned& b) {
    asm("v_permlane32_swap_b32 %0, %1" : "+v"(a), "+v"(b));
}
// swizzled elem offset within a linear [64][64] bf16 LDS tile (attn)
__device__ inline int swz(int row, int col) {
    return row * 64 + (col ^ ((row & 7) << 3));
}
// XCD-aware chunked remap (bijective, nwg % 8 == 0)
__device__ inline int xcd_swz(int bid, int nwg) {
    return (bid & 7) * (nwg >> 3) + (bid >> 3);
}
// async global->LDS, 16B per lane; LDS dest = wave-uniform base + lane*16
__device__ __attribute__((always_inline)) inline void gload16(
    const ushort_t* g, ushort_t* l)
{
    __builtin_amdgcn_global_load_lds(
        (const __attribute__((address_space(1))) void*)g,
        (__attribute__((address_space(3))) void*)l, 16, 0, 0);
}

// ---------------------------------------------------------------------------
// Prep: f32 -> bf16 converts (R16-exact)
// ---------------------------------------------------------------------------
__global__ __launch_bounds__(256) void cvt2(
    const float* __restrict__ s0, ushort_t* __restrict__ d0,
    const float* __restrict__ s1, ushort_t* __restrict__ d1, int n8)
{
    const float* s = blockIdx.y ? s1 : s0;
    ushort_t*    d = blockIdx.y ? d1 : d0;
    int i = blockIdx.x * 256 + threadIdx.x;
    if (i >= n8) return;
    const f32x4* sp = (const f32x4*)s + (size_t)i * 2;
    f32x4 a = sp[0], b = sp[1];
    ushort8 o;
    for (int k = 0; k < 4; ++k) { o[k] = fcvt(a[k]); o[k + 4] = fcvt(b[k]); }
    *((ushort8*)d + i) = o;
}

__global__ __launch_bounds__(256) void cvt4(
    const float* __restrict__ s0, ushort_t* __restrict__ d0,
    const float* __restrict__ s1, ushort_t* __restrict__ d1,
    const float* __restrict__ s2, ushort_t* __restrict__ d2,
    const float* __restrict__ s3, ushort_t* __restrict__ d3, int n8)
{
    const float* ss[4] = {s0, s1, s2, s3};
    ushort_t*    dd[4] = {d0, d1, d2, d3};
    const float* s = ss[blockIdx.y];
    ushort_t*    d = dd[blockIdx.y];
    int i = blockIdx.x * 256 + threadIdx.x;
    if (i >= n8) return;
    const f32x4* sp = (const f32x4*)s + (size_t)i * 2;
    f32x4 a = sp[0], b = sp[1];
    ushort8 o;
    for (int k = 0; k < 4; ++k) { o[k] = fcvt(a[k]); o[k + 4] = fcvt(b[k]); }
    *((ushort8*)d + i) = o;
}

// ---------------------------------------------------------------------------
// GEMM core (R16-exact).  Tile BM x BN, BK=32, 4 waves 2x2.
// global_load_lds 16B staging, source-chunk swizzle, 1 barrier/K-step.
// ---------------------------------------------------------------------------
template<int BM, int BN>
__device__ __attribute__((always_inline)) inline void gemm_core3(
    const ushort_t* __restrict__ A, const ushort_t* __restrict__ W,
    int m0, int n0, int tid, f32x4 (&acc)[BM / 32][BN / 32], ushort_t* sLDS)
{
    constexpr int TA = BM * 32;            // A tile elems
    constexpr int TB = BN * 32;            // B tile elems
    ushort_t* const aB0 = sLDS;
    ushort_t* const aB1 = sLDS + TA;
    ushort_t* const bB0 = sLDS + 2 * TA;
    ushort_t* const bB1 = sLDS + 2 * TA + TB;

    const int w    = tid >> 6;
    const int lane = tid & 63;
    const int quad = lane >> 4;
    const int l15  = lane & 15;
    const int wm   = w >> 1;
    const int wn   = w & 1;

    // staging: 4 lanes/row, 16 rows per gload; source chunk swizzled
    const int srow = lane >> 2;                        // 0..15
    const int sch  = (((lane & 3) ^ ((lane >> 3) & 3)) << 3);  // elems
    const ushort_t* Ag = A + (size_t)(m0 + w * (BM / 4) + srow) * DIM + sch;
    const ushort_t* Bg = W + (size_t)(n0 + w * (BN / 4) + srow) * DIM + sch;
    const int aOff = w * (BM / 4) * 32;    // elems
    const int bOff = w * (BN / 4) * 32;

    // prologue: stage tile 0 into buffer 0
    for (int i = 0; i < BM / 64; ++i)
        gload16(Ag + (size_t)(i * 16) * DIM, aB0 + aOff + i * 512);
    for (int i = 0; i < BN / 64; ++i)
        gload16(Bg + (size_t)(i * 16) * DIM, bB0 + bOff + i * 512);
    __syncthreads();

    const int slot = (quad ^ ((l15 >> 1) & 3)) << 3;   // read-side elem off
    for (int it = 0; it < DIM / 32; ++it) {
        const int cur = it & 1;
        ushort_t* aC = cur ? aB1 : aB0;
        ushort_t* bC = cur ? bB1 : bB0;
        ushort_t* aN = cur ? aB0 : aB1;
        ushort_t* bN = cur ? bB0 : bB1;

        if (it + 1 < DIM / 32) {
            const int k0 = (it + 1) * 32;
            for (int i = 0; i < BM / 64; ++i)
                gload16(Ag + k0 + (size_t)(i * 16) * DIM, aN + aOff + i * 512);
            for (int i = 0; i < BN / 64; ++i)
                gload16(Bg + k0 + (size_t)(i * 16) * DIM, bN + bOff + i * 512);
        }

        bf16x8 af[BM / 32], bf[BN / 32];
        for (int i = 0; i < BM / 32; ++i) {
            int row = wm * (BM / 2) + i * 16 + l15;
            af[i] = lds_frag(aC + row * 32 + slot);
        }
        for (int j = 0; j < BN / 32; ++j) {
            int row = wn * (BN / 2) + j * 16 + l15;
            bf[j] = lds_frag(bC + row * 32 + slot);
        }
        for (int i = 0; i < BM / 32; ++i)
            for (int j = 0; j < BN / 32; ++j)
                acc[i][j] = __builtin_amdgcn_mfma_f32_16x16x32_bf16(
                    af[i], bf[j], acc[i][j], 0, 0, 0);
        __syncthreads();
    }
}

// Fused Q/K/V projections: z = 0 (Q, scaled), 1 (K), 2 (V, transposed out).
// 1D grid 768, XCD-swizzled; logical tile = z*256 + my*8 + nx.
__global__ __launch_bounds__(256, 3) void proj3(
    const ushort_t* __restrict__ Qb, const ushort_t* __restrict__ KVb,
    const ushort_t* __restrict__ qwb, const ushort_t* __restrict__ kwb,
    const ushort_t* __restrict__ vwb,
    const float* __restrict__ q_b, const float* __restrict__ k_b,
    const float* __restrict__ v_b,
    ushort_t* __restrict__ Qp, ushort_t* __restrict__ Kp,
    ushort_t* __restrict__ VpT)
{
    __shared__ __align__(1024) ushort_t sLDS[17536];   // 35072 B

    const int lb = xcd_swz(blockIdx.x, 768);
    const int z  = lb >> 8;                // 0..2
    const int r  = lb & 255;
    const int m0 = (r >> 3) * 128;
    const int n0 = (r & 7) * 128;

    const ushort_t* A = z ? KVb : Qb;
    const ushort_t* W = (z == 0) ? qwb : (z == 1 ? kwb : vwb);
    const float* bias = (z == 0) ? q_b : (z == 1 ? k_b : v_b);
    const int tid = threadIdx.x;

    f32x4 acc[4][4] = {};
    gemm_core3<128, 128>(A, W, m0, n0, tid, acc, sLDS);

    const int lane = tid & 63, quad = lane >> 4, l15 = lane & 15;
    const int wm = (tid >> 6) >> 1, wn = (tid >> 6) & 1;

    if (z == 2) {
        // V^T epilogue: transpose 128x128 C-tile through LDS, coalesced out.
        const int TSTR = 136;                // row stride: 272B, 16B-aligned
        for (int j = 0; j < 4; ++j) {
            int col = wn * 64 + j * 16 + l15;           // tile-local n
            float bj = bias[n0 + col];
            for (int i = 0; i < 4; ++i) {
                int row = wm * 64 + i * 16 + quad * 4;  // tile-local m
                ushort4v o4;
                for (int r2 = 0; r2 < 4; ++r2) o4[r2] = fcvt(acc[i][j][r2] + bj);
                *(ushort4v*)(sLDS + col * TSTR + row) = o4;
            }
        }
        __syncthreads();
        const int vrow = tid >> 1;           // 0..127  (V^T row = tile col)
        const int vc   = (tid & 1) * 64;
        ushort_t* dst = VpT + (size_t)(n0 + vrow) * SEQ + m0 + vc;
        const ushort_t* src = sLDS + vrow * TSTR + vc;
        for (int k = 0; k < 8; ++k)
            *(ushort8*)(dst + k * 8) = *(const ushort8*)(src + k * 8);
    } else {
        const float scale = (z == 0) ? QSCALE : 1.0f;
        ushort_t* C = z ? Kp : Qp;
        for (int j = 0; j < 4; ++j) {
            int col = n0 + wn * 64 + j * 16 + l15;
            float bj = bias[col];
            for (int i = 0; i < 4; ++i) {
                int row = m0 + wm * 64 + i * 16 + quad * 4;
                for (int r2 = 0; r2 < 4; ++r2)
                    C[(size_t)(row + r2) * DIM + col] =
                        fcvt((acc[i][j][r2] + bj) * scale);
            }
        }
    }
}

// O projection: f32 output.  64x64 tile, BK=32, 16KB LDS.
// 1D grid 1024, XCD-swizzled; logical tile = my*16 + nx (m-major).
__global__ __launch_bounds__(256, 4) void gemm_out(
    const ushort_t* __restrict__ A, const ushort_t* __restrict__ W,
    const float* __restrict__ bias, float* __restrict__ C)
{
    __shared__ __align__(1024) ushort_t sLDS[8192];    // 16 KB

    const int lb = xcd_swz(blockIdx.x, 1024);
    const int m0 = (lb >> 4) * 64;
    const int n0 = (lb & 15) * 64;
    const int tid = threadIdx.x;

    f32x4 acc[2][2] = {};
    gemm_core3<64, 64>(A, W, m0, n0, tid, acc, sLDS);

    const int lane = tid & 63, quad = lane >> 4, l15 = lane & 15;
    const int wm = (tid >> 6) >> 1, wn = (tid >> 6) & 1;
    for (int j = 0; j < 2; ++j) {
        int col = n0 + wn * 32 + j * 16 + l15;
        float bj = bias[col];
        for (int i = 0; i < 2; ++i) {
            int row = m0 + wm * 32 + i * 16 + quad * 4;
            for (int r = 0; r < 4; ++r)
                C[(size_t)(row + r) * DIM + col] = acc[i][j][r] + bj;
        }
    }
}

// ---------------------------------------------------------------------------
// Flash attention — R15/R20 math, T15-pipelined.  4 waves x 32 q rows,
// full KV sweep.  PV(it-1) runs inside iter it (independent MFMA under
// QK(it) latency + exp2(it) VALU); P(prev) carried packed in pf_p, V(prev)
// in vf_p.  V's ds_read placed AFTER the PV that consumes the old vf_p.
// Accumulation order into oacc / l_i is identical to R20 -> bit-exact.
// 1D grid 512 + XCD swizzle.  1 barrier/iter.
// ---------------------------------------------------------------------------
#define TILE 4096                  // elems per 64x64 bf16 tile
#define BUFE (2 * TILE)            // K tile + V tile per buffer
__global__ __launch_bounds__(256, 2) void attn_kernel(
    const ushort_t* __restrict__ Q, const ushort_t* __restrict__ K,
    const ushort_t* __restrict__ VT, ushort_t* __restrict__ O)
{
    __shared__ __align__(16) ushort_t sB[2 * BUFE];   // 32768 B

    const int lb   = xcd_swz(blockIdx.x, 512);
    const int h    = lb >> 5;
    const int qblk = lb & 31;

    const int tid  = threadIdx.x;
    const int w    = tid >> 6;
    const int lane = tid & 63;
    const int l31  = lane & 31;
    const int hi   = lane >> 5;
    const int q0   = qblk * 128 + w * 32;
    const int hHD  = h * HD;

    const int srow0 = tid >> 3;
    const int srow1 = srow0 + 32;
    const int sch   = (tid & 7) << 3;
    const ushort_t* Kg0 = K  + (size_t)srow0 * DIM + hHD + sch;
    const ushort_t* Kg1 = K  + (size_t)srow1 * DIM + hHD + sch;
    const ushort_t* Vg0 = VT + (size_t)(hHD + srow0) * SEQ + sch;
    const ushort_t* Vg1 = VT + (size_t)(hHD + srow1) * SEQ + sch;
    const int lk0 = swz(srow0, sch), lk1 = swz(srow1, sch);

    const ushort_t* qb = Q + (size_t)(q0 + l31) * DIM + hHD + hi * 8;
    bf16x8 qf[4];
    for (int ks = 0; ks < 4; ++ks)
        qf[ks] = frag_of(*(const ushort8*)(qb + ks * 16));

    // prologue: stage kv tile 0 into buffer 0
    *(ushort8*)(sB + lk0)        = *(const ushort8*)(Kg0);
    *(ushort8*)(sB + lk1)        = *(const ushort8*)(Kg1);
    *(ushort8*)(sB + TILE + lk0) = *(const ushort8*)(Vg0);
    *(ushort8*)(sB + TILE + lk1) = *(const ushort8*)(Vg1);
    __syncthreads();

    f32x16 oacc[2] = {};
    float l_i = 0.f;
    uint4v pf_p[4];                // packed P of tile it-1
    bf16x8 vf_p[8];                // V fragments of tile it-1

    // ---- iter 0: QK + softmax only (no PV yet) ----
    {
        ushort8 gk0 = *(const ushort8*)(Kg0 + (size_t)64 * DIM);
        ushort8 gk1 = *(const ushort8*)(Kg1 + (size_t)64 * DIM);
        ushort8 gv0 = *(const ushort8*)(Vg0 + 64);
        ushort8 gv1 = *(const ushort8*)(Vg1 + 64);

        bf16x8 kf[8];
        for (int t = 0; t < 2; ++t)
            for (int ks = 0; ks < 4; ++ks) {
                int r = t * 32 + l31;
                kf[t * 4 + ks] = lds_frag(sB + swz(r, ks * 16 + hi * 8));
            }
        for (int dt = 0; dt < 2; ++dt)
            for (int ks = 0; ks < 4; ++ks) {
                int r = dt * 32 + l31;
                vf_p[ks * 2 + dt] = lds_frag(sB + TILE + swz(r, ks * 16 + hi * 8));
            }

        f32x16 sacc[2] = {};
        for (int t = 0; t < 2; ++t)
            for (int ks = 0; ks < 4; ++ks)
                sacc[t] = __builtin_amdgcn_mfma_f32_32x32x16_bf16(
                    kf[t * 4 + ks], qf[ks], sacc[t], 0, 0, 0);

        float lp = 0.f;
        for (int t = 0; t < 2; ++t)
            for (int r = 0; r < 16; ++r) {
                float p = __builtin_amdgcn_exp2f(sacc[t][r]);
                sacc[t][r] = p;
                lp += p;
            }
        l_i += lp + __shfl_xor(lp, 32);

        for (int ks = 0; ks < 4; ++ks) {
            const int t = ks >> 1, s8 = (ks & 1) * 8;
            unsigned p00 = pk2(sacc[t][s8 + 0], sacc[t][s8 + 1]);
            unsigned p01 = pk2(sacc[t][s8 + 2], sacc[t][s8 + 3]);
            unsigned p10 = pk2(sacc[t][s8 + 4], sacc[t][s8 + 5]);
            unsigned p11 = pk2(sacc[t][s8 + 6], sacc[t][s8 + 7]);
            plswap(p00, p10);
            plswap(p01, p11);
            uint4v wv; wv[0] = p00; wv[1] = p01; wv[2] = p10; wv[3] = p11;
            pf_p[ks] = wv;
        }

        ushort_t* nB = sB + BUFE;
        *(ushort8*)(nB + lk0)        = gk0;
        *(ushort8*)(nB + lk1)        = gk1;
        *(ushort8*)(nB + TILE + lk0) = gv0;
        *(ushort8*)(nB + TILE + lk1) = gv1;
        __syncthreads();
    }

    // ---- iters 1..63: QK(it) + PV(it-1) overlapped ----
    for (int it = 1; it < SEQ / 64; ++it) {
        const int cur = it & 1;
        const int kvn = (it + 1) * 64;
        ushort_t* bK = sB + cur * BUFE;
        ushort_t* bV = bK + TILE;

        ushort8 gk0, gk1, gv0, gv1;
        if (kvn < SEQ) {
            gk0 = *(const ushort8*)(Kg0 + (size_t)kvn * DIM);
            gk1 = *(const ushort8*)(Kg1 + (size_t)kvn * DIM);
            gv0 = *(const ushort8*)(Vg0 + kvn);
            gv1 = *(const ushort8*)(Vg1 + kvn);
        }

        bf16x8 kf[8];
        for (int t = 0; t < 2; ++t)
            for (int ks = 0; ks < 4; ++ks) {
                int r = t * 32 + l31;
                kf[t * 4 + ks] = lds_frag(bK + swz(r, ks * 16 + hi * 8));
            }

        // QK(it): lane l31 = q col, regs = kv rows
        f32x16 sacc[2] = {};
        for (int t = 0; t < 2; ++t)
            for (int ks = 0; ks < 4; ++ks)
                sacc[t] = __builtin_amdgcn_mfma_f32_32x32x16_bf16(
                    kf[t * 4 + ks], qf[ks], sacc[t], 0, 0, 0);

        // PV(it-1): independent of QK(it) — fills the MFMA pipe while
        // QK results and exp2 are in flight.
        for (int ks = 0; ks < 4; ++ks) {
            bf16x8 pf = __builtin_bit_cast(bf16x8, pf_p[ks]);
            for (int dt = 0; dt < 2; ++dt)
                oacc[dt] = __builtin_amdgcn_mfma_f32_32x32x16_bf16(
                    vf_p[ks * 2 + dt], pf, oacc[dt], 0, 0, 0);
        }

        // old vf_p consumed -> load V(it) into the same registers
        for (int dt = 0; dt < 2; ++dt)
            for (int ks = 0; ks < 4; ++ks) {
                int r = dt * 32 + l31;
                vf_p[ks * 2 + dt] = lds_frag(bV + swz(r, ks * 16 + hi * 8));
            }

        float lp = 0.f;
        for (int t = 0; t < 2; ++t)
            for (int r = 0; r < 16; ++r) {
                float p = __builtin_amdgcn_exp2f(sacc[t][r]);
                sacc[t][r] = p;
                lp += p;
            }
        l_i += lp + __shfl_xor(lp, 32);

        for (int ks = 0; ks < 4; ++ks) {
            const int t = ks >> 1, s8 = (ks & 1) * 8;
            unsigned p00 = pk2(sacc[t][s8 + 0], sacc[t][s8 + 1]);
            unsigned p01 = pk2(sacc[t][s8 + 2], sacc[t][s8 + 3]);
            unsigned p10 = pk2(sacc[t][s8 + 4], sacc[t][s8 + 5]);
            unsigned p11 = pk2(sacc[t][s8 + 6], sacc[t][s8 + 7]);
            plswap(p00, p10);
            plswap(p01, p11);
            uint4v wv; wv[0] = p00; wv[1] = p01; wv[2] = p10; wv[3] = p11;
            pf_p[ks] = wv;
        }

        if (kvn < SEQ) {
            ushort_t* nB = sB + (cur ^ 1) * BUFE;
            *(ushort8*)(nB + lk0)        = gk0;
            *(ushort8*)(nB + lk1)        = gk1;
            *(ushort8*)(nB + TILE + lk0) = gv0;
            *(ushort8*)(nB + TILE + lk1) = gv1;
        }
        __syncthreads();
    }

    // ---- epilogue: PV(63) ----
    for (int ks = 0; ks < 4; ++ks) {
        bf16x8 pf = __builtin_bit_cast(bf16x8, pf_p[ks]);
        for (int dt = 0; dt < 2; ++dt)
            oacc[dt] = __builtin_amdgcn_mfma_f32_32x32x16_bf16(
                vf_p[ks * 2 + dt], pf, oacc[dt], 0, 0, 0);
    }

    float inv = 1.f / l_i;
    int qrow = q0 + l31;
    for (int dt = 0; dt < 2; ++dt)
        for (int g = 0; g < 4; ++g) {
            ushort4v o4;
            for (int r = 0; r < 4; ++r) o4[r] = fcvt(oacc[dt][g * 4 + r] * inv);
            *(ushort4v*)(O + (size_t)qrow * DIM + hHD + dt * 32 + g * 8 + hi * 4) = o4;
        }
}

// ---------------------------------------------------------------------------
extern "C" void kernel_launch(void* const* d_in, const int* in_sizes, int n_in,
                              void* d_out, int out_size, void* d_ws, size_t ws_size,
                              hipStream_t stream)
{
    const float* q   = (const float*)d_in[0];
    const float* kv  = (const float*)d_in[1];
    const float* q_w = (const float*)d_in[2];
    const float* q_b = (const float*)d_in[3];
    const float* k_w = (const float*)d_in[4];
    const float* k_b = (const float*)d_in[5];
    const float* v_w = (const float*)d_in[6];
    const float* v_b = (const float*)d_in[7];
    const float* o_w = (const float*)d_in[8];
    const float* o_b = (const float*)d_in[9];
    float* out = (float*)d_out;

    const size_t SD = (size_t)SEQ * DIM;
    const size_t WW = (size_t)DIM * DIM;
    ushort_t* Qp  = (ushort_t*)d_ws;          // bf16, pre-scaled by QSCALE
    ushort_t* Kp  = Qp + SD;
    ushort_t* VpT = Kp + SD;                  // V^T: [DIM][SEQ]
    ushort_t* AO  = VpT + SD;                 // attention out; aliases Qb
    ushort_t* Qb  = AO;                       // bf16(q) — dead before AO write
    ushort_t* KVb = AO + SD;
    ushort_t* qwb = KVb + SD;
    ushort_t* kwb = qwb + WW;
    ushort_t* vwb = kwb + WW;
    ushort_t* owb = vwb + WW;

    cvt2<<<dim3((unsigned)(SD / 8 / 256), 2), 256, 0, stream>>>(
        q, Qb, kv, KVb, (int)(SD / 8));
    cvt4<<<dim3((unsigned)(WW / 8 / 256), 4), 256, 0, stream>>>(
        q_w, qwb, k_w, kwb, v_w, vwb, o_w, owb, (int)(WW / 8));

    proj3<<<dim3(768), 256, 0, stream>>>(
        Qb, KVb, qwb, kwb, vwb, q_b, k_b, v_b, Qp, Kp, VpT);
    attn_kernel<<<dim3(512), 256, 0, stream>>>(Qp, Kp, VpT, AO);
    gemm_out<<<dim3(1024), 256, 0, stream>>>(AO, owb, o_b, out);
}